// Round 7
// baseline (1546.600 us; speedup 1.0000x reference)
//
#include <hip/hip_runtime.h>
#include <stdint.h>

#define TSTEPS 2048
#define L2E 1.4426950408889634f   // log2(e)

typedef _Float16 half8 __attribute__((ext_vector_type(8)));
typedef _Float16 half4 __attribute__((ext_vector_type(4)));
typedef float    f32x4 __attribute__((ext_vector_type(4)));

// 4 independent waves per 256-thread WG (no barriers); each wave owns 2
// batch sequences -> 4096 waves = 4/SIMD (16 waves/CU via 4 WGs/CU).
// Per wave-step:
//   acc[n] = mfma_16x16x32_f16(A_hdup, Whh_tile_n,
//            mfma_16x16x16f16(a2, B2_tile_n, 0))         // n = 0..7
// A_hdup rows m = h[batch m>>3] (8x dup); a2 = {x_t, 1, 0...} with
// B2 = rows {wih*s, bias*s} -> x-projection + bias ride the MFMA pipe,
// C is a hoisted zero, acc is iteration-dead (stays in VGPRs, no AGPR
// round-trips). D mapping (m89-verified: row=(lane>>4)*4+r, col=lane&15):
// element r=0 of acc[2t+p] = gate t of cell (batch=quad>>1,
// unit=cidx+16p), p=quad&1 -> 4 cndmask selects, rest compile-time.
// One cell/lane: 5 exp2 + 3 rcp (fused sigmoid*tanh forms, exact algebra):
//   sig(i)*tanh(g) = (eg-1)/[(1+ei)(1+eg)],  eg=e^{2g}, ei=e^{-i}
//   sig(o)*tanh(c) = (ec-1)/[(1+eo)(1+ec)]
// Weights pre-scaled by -log2e (i,f,o) / +2log2e (g) so v_exp_f32 (2^x)
// consumes the accumulator directly. tanh-input c clamped to +-15
// (stored c unclamped; gate preacts are bounded so only c could overflow).
// h feedback: 128 B/wave f16 LDS, write addr == lane; in-order DS pipe +
// lgkmcnt(0) fence (r2/r5-verified pattern).
extern "C" __global__ void __launch_bounds__(256, 4)
lstm_w2(const float* __restrict__ x,     // [B, T]
        const float* __restrict__ W_ih,  // [128]
        const float* __restrict__ W_hh,  // [128, 32]
        const float* __restrict__ b_ih,  // [128]
        const float* __restrict__ b_hh,  // [128]
        const float* __restrict__ W3,    // [32, 32]
        const float* __restrict__ b3,    // [32]
        const float* __restrict__ W4,    // [32]
        const float* __restrict__ b4,    // [1]
        float* __restrict__ out)         // [B]
{
    const int tid  = threadIdx.x;
    const int wid  = tid >> 6;             // wave 0..3 (independent)
    const int lane = tid & 63;
    const int cidx = lane & 15;
    const int quad = lane >> 4;
    const bool ph  = (quad & 1) != 0;      // unit-half selector
    const int wb   = blockIdx.x * 8 + wid * 2;   // 2 batches per wave

    __shared__ _Float16 hsh[4][64];        // per-wave h[2][32], 128 B

    // ---- loop-invariant fragments ----
    // bfrag[n]: W_hh B-frag for 16x16x32, lane holds B[k=quad*8+q][16n+cidx]
    // b2frag[n]: x-proj B-frag for 16x16x16, rows k=0 (wih*s), k=1 (bias*s)
    half8 bfrag[8];
    half4 b2frag[8];
    #pragma unroll
    for (int n = 0; n < 8; ++n) {
        const int g = 16 * n + cidx;
        const float s = (n == 4 || n == 5) ? (2.0f * L2E) : (-L2E);
        const float* wr = W_hh + g * 32 + quad * 8;
        float4 w0 = *(const float4*)(wr);
        float4 w1 = *(const float4*)(wr + 4);
        half8 hb;
        hb[0] = (_Float16)(w0.x * s); hb[1] = (_Float16)(w0.y * s);
        hb[2] = (_Float16)(w0.z * s); hb[3] = (_Float16)(w0.w * s);
        hb[4] = (_Float16)(w1.x * s); hb[5] = (_Float16)(w1.y * s);
        hb[6] = (_Float16)(w1.z * s); hb[7] = (_Float16)(w1.w * s);
        bfrag[n] = hb;
        half4 b2;
        b2[0] = (_Float16)0.0f; b2[1] = (_Float16)0.0f;
        b2[2] = (_Float16)0.0f; b2[3] = (_Float16)0.0f;
        if (quad == 0) {                   // only k=0,1 rows are nonzero
            b2[0] = (_Float16)(W_ih[g] * s);
            b2[1] = (_Float16)((b_ih[g] + b_hh[g]) * s);
        }
        b2frag[n] = b2;
    }

    float c = 0.0f;                        // cell state (fp32, exact)
    hsh[wid][lane] = (_Float16)0.0f;       // write addr == lane (see map)
    asm volatile("s_waitcnt lgkmcnt(0)" ::: "memory");

    // x for this lane's A2-row batch: row=cidx -> batch cidx>>3
    const float* xp = x + (size_t)(wb + (cidx >> 3)) * TSTEPS;
    float4 xnext = *(const float4*)(xp);

    // a2 = {x_t, 1, dc, dc}: slots k>=2 multiply zero B2 rows (don't-care),
    // so every lane writes x into elem 0 regardless of quad.
    half4 a2;
    a2[0] = (_Float16)0.0f; a2[1] = (_Float16)1.0f;
    a2[2] = (_Float16)0.0f; a2[3] = (_Float16)0.0f;

    const char* hb8 = (const char*)&hsh[wid][0];
    const int abyte = (cidx >> 3) * 64 + quad * 16;  // A[m=cidx][k=quad*8+q]

    for (int t0 = 0; t0 < TSTEPS; t0 += 4) {
        float4 xc = xnext;
        if (t0 + 4 < TSTEPS) xnext = *(const float4*)(xp + t0 + 4);
        #pragma unroll
        for (int tt = 0; tt < 4; ++tt) {
            union { uint4 u4; half8 h; } af;
            af.u4 = *(const uint4*)(hb8 + abyte);

            a2[0] = (_Float16)(((const float*)&xc)[tt]);

            f32x4 acc[8];
            #pragma unroll
            for (int n = 0; n < 8; ++n) {
                f32x4 z; z[0] = 0.f; z[1] = 0.f; z[2] = 0.f; z[3] = 0.f;
                f32x4 xb = __builtin_amdgcn_mfma_f32_16x16x16f16(
                               a2, b2frag[n], z, 0, 0, 0);
                acc[n] = __builtin_amdgcn_mfma_f32_16x16x32_f16(
                               af.h, bfrag[n], xb, 0, 0, 0);
            }

            // gate select: tile 2t+p, element 0 (compile-time reg)
            float ai = ph ? acc[1][0] : acc[0][0];
            float av = ph ? acc[3][0] : acc[2][0];
            float ag = ph ? acc[5][0] : acc[4][0];
            float ao = ph ? acc[7][0] : acc[6][0];

            float ei = __builtin_amdgcn_exp2f(ai);   // e^{-i}
            float ef = __builtin_amdgcn_exp2f(av);   // e^{-f}
            float eg = __builtin_amdgcn_exp2f(ag);   // e^{2g}
            float eo = __builtin_amdgcn_exp2f(ao);   // e^{-o}
            float p1 = 1.0f + ei, p2 = 1.0f + eg;
            float p3 = 1.0f + ef, p4 = 1.0f + eo;
            float sf  = __builtin_amdgcn_rcpf(p3);           // sigmoid(f)
            float rig = __builtin_amdgcn_rcpf(p1 * p2);
            c = fmaf(sf, c, (eg - 1.0f) * rig);              // f*c + i*g
            float cc = fminf(fmaxf(c, -15.0f), 15.0f);       // med3 clamp
            float ec = __builtin_amdgcn_exp2f(cc * (2.0f * L2E));
            float rh = __builtin_amdgcn_rcpf(p4 * (1.0f + ec));
            float hv = (ec - 1.0f) * rh;                     // sig(o)*tanh(c)
            hsh[wid][lane] = (_Float16)hv;
            asm volatile("s_waitcnt lgkmcnt(0)" ::: "memory");
        }
    }

    // ---- head: 2 batches/wave; lane j=lane&31 (unit), g0=lane>>5 (batch)
    const int j  = lane & 31;
    const int g0 = lane >> 5;
    float a = b3[j];
    #pragma unroll
    for (int k = 0; k < 32; ++k)
        a = fmaf((float)hsh[wid][g0 * 32 + k], W3[j * 32 + k], a);
    a = fmaxf(a, 0.0f);
    float v = a * W4[j];
    #pragma unroll
    for (int off = 16; off >= 1; off >>= 1)   // stays within 32-lane halves
        v += __shfl_xor(v, off);
    if ((lane & 31) == 0) {
        float e = __builtin_amdgcn_exp2f(-(v + b4[0]) * L2E);
        out[wb + g0] = __builtin_amdgcn_rcpf(1.0f + e);
    }
}

extern "C" void kernel_launch(void* const* d_in, const int* in_sizes, int n_in,
                              void* d_out, int out_size, void* d_ws, size_t ws_size,
                              hipStream_t stream) {
    const float* x    = (const float*)d_in[0];
    const float* W_ih = (const float*)d_in[1];
    const float* W_hh = (const float*)d_in[2];
    const float* b_ih = (const float*)d_in[3];
    const float* b_hh = (const float*)d_in[4];
    const float* W3   = (const float*)d_in[5];
    const float* b3   = (const float*)d_in[6];
    const float* W4   = (const float*)d_in[7];
    const float* b4   = (const float*)d_in[8];
    float* out = (float*)d_out;

    const int batches = out_size;          // 8192
    const int blocks  = batches / 8;       // 1024 WGs x 4 waves x 2 batches
    lstm_w2<<<blocks, 256, 0, stream>>>(x, W_ih, W_hh, b_ih, b_hh,
                                        W3, b3, W4, b4, out);
}

// Round 8
// 1078.828 us; speedup vs baseline: 1.4336x; 1.4336x over previous
//
#include <hip/hip_runtime.h>
#include <stdint.h>

#define TSTEPS 2048
#define L2E 1.4426950408889634f   // log2(e)

typedef _Float16 half8 __attribute__((ext_vector_type(8)));
typedef float    f32x4 __attribute__((ext_vector_type(4)));

// 4 independent waves per 256-thread WG (no barriers); each wave owns 2
// batch sequences -> 4096 waves = 4/SIMD. Per wave-step: 8 VALU FMAs init
// acc[n][0] (r5-style, chained-MFMA variant measured slower in r7), then
// 8x mfma_f32_16x16x32_f16 with 8x-row-duplicated A (A[m]=h[batch m>>3]).
// D mapping (m89-verified: row=(lane>>4)*4+r, col=lane&15): elem 0 of
// acc[2t+p] = gate t of cell (batch=quad>>1, unit=cidx+16p), p=quad&1.
// Unused acc rows accumulate bounded garbage (never overflows, never read).
//
// Activation: 7 trans/cell (5 exp2 + 2 rcp), exact algebra with shared
// denominator (weights pre-scaled by -log2e for i,f,o and +2log2e for g):
//   ei=e^-i ef=e^-f eg=e^2g; p1=1+ei p2=1+eg p3=1+ef
//   c' = (c*p1p2 + (eg-1)*p3) / (p3*p1p2)        [sig(f)*c + sig(i)tanh(g)]
//   h  = (ec-1) / ((1+eo)(1+ec)),  ec=e^{2*clamp(c',+-15)}
//
// h feedback: 128 B/wave f16 LDS slice, write addr == lane, read b128 at
// (cidx>>3)*64+quad*16. Same-wave DS ops execute in order -> no hardware
// fence needed; a compiler-only barrier keeps the write->read program order,
// and the compiler auto-inserts lgkmcnt before the MFMA consumes the read.
extern "C" __global__ void __launch_bounds__(256, 4)
lstm_v8(const float* __restrict__ x,     // [B, T]
        const float* __restrict__ W_ih,  // [128]
        const float* __restrict__ W_hh,  // [128, 32]
        const float* __restrict__ b_ih,  // [128]
        const float* __restrict__ b_hh,  // [128]
        const float* __restrict__ W3,    // [32, 32]
        const float* __restrict__ b3,    // [32]
        const float* __restrict__ W4,    // [32]
        const float* __restrict__ b4,    // [1]
        float* __restrict__ out)         // [B]
{
    const int tid  = threadIdx.x;
    const int wid  = tid >> 6;             // wave 0..3 (independent)
    const int lane = tid & 63;
    const int cidx = lane & 15;
    const int quad = lane >> 4;
    const bool ph  = (quad & 1) != 0;      // unit-half selector
    const int myb  = quad >> 1;            // this lane's batch (0/1)
    const int wb   = blockIdx.x * 8 + wid * 2;   // 2 batches per wave

    __shared__ _Float16 hsh[4][64];        // per-wave h[2][32], 128 B

    // ---- loop-invariant fragments ----
    // bfrag[n]: W_hh B-frag, lane holds B[k=quad*8+q][gatecol=16n+cidx]
    half8 bfrag[8];
    float wihs[8], biass[8];
    #pragma unroll
    for (int n = 0; n < 8; ++n) {
        const int g = 16 * n + cidx;
        const float s = (n == 4 || n == 5) ? (2.0f * L2E) : (-L2E);
        const float* wr = W_hh + g * 32 + quad * 8;
        float4 w0 = *(const float4*)(wr);
        float4 w1 = *(const float4*)(wr + 4);
        half8 hb;
        hb[0] = (_Float16)(w0.x * s); hb[1] = (_Float16)(w0.y * s);
        hb[2] = (_Float16)(w0.z * s); hb[3] = (_Float16)(w0.w * s);
        hb[4] = (_Float16)(w1.x * s); hb[5] = (_Float16)(w1.y * s);
        hb[6] = (_Float16)(w1.z * s); hb[7] = (_Float16)(w1.w * s);
        bfrag[n] = hb;
        wihs[n]  = W_ih[g] * s;
        biass[n] = (b_ih[g] + b_hh[g]) * s;
    }

    float c = 0.0f;                        // cell state (fp32)
    hsh[wid][lane] = (_Float16)0.0f;
    asm volatile("" ::: "memory");         // compiler order only

    // x for this lane's OWN batch (C-init needs it); 32 lanes share an addr
    const float* xp = x + (size_t)(wb + myb) * TSTEPS;
    float4 xnext = *(const float4*)(xp);

    f32x4 acc[8];
    #pragma unroll
    for (int n = 0; n < 8; ++n) acc[n] = (f32x4){0.f, 0.f, 0.f, 0.f};

    const char* hb8 = (const char*)&hsh[wid][0];
    const int abyte = (cidx >> 3) * 64 + quad * 16;  // A[m=cidx][k=quad*8+q]

    for (int t0 = 0; t0 < TSTEPS; t0 += 4) {
        float4 xc = xnext;
        if (t0 + 4 < TSTEPS) xnext = *(const float4*)(xp + t0 + 4);
        #pragma unroll
        for (int tt = 0; tt < 4; ++tt) {
            union { uint4 u4; half8 h; } af;
            af.u4 = *(const uint4*)(hb8 + abyte);

            const float xs = ((const float*)&xc)[tt];
            #pragma unroll
            for (int n = 0; n < 8; ++n)
                acc[n][0] = fmaf(xs, wihs[n], biass[n]);

            #pragma unroll
            for (int n = 0; n < 8; ++n)
                acc[n] = __builtin_amdgcn_mfma_f32_16x16x32_f16(
                             af.h, bfrag[n], acc[n], 0, 0, 0);

            // gate select: tile 2t+p, element 0 (compile-time reg)
            float ai = ph ? acc[1][0] : acc[0][0];
            float av = ph ? acc[3][0] : acc[2][0];
            float ag = ph ? acc[5][0] : acc[4][0];
            float ao = ph ? acc[7][0] : acc[6][0];

            float ei = __builtin_amdgcn_exp2f(ai);   // e^{-i}
            float ef = __builtin_amdgcn_exp2f(av);   // e^{-f}
            float eg = __builtin_amdgcn_exp2f(ag);   // e^{2g}
            float p1 = 1.0f + ei, p2 = 1.0f + eg, p3 = 1.0f + ef;
            float q12 = p1 * p2;
            float den = p3 * q12;
            float num = fmaf(c, q12, (eg - 1.0f) * p3);
            c = num * __builtin_amdgcn_rcpf(den);    // f*c + i*g
            float cc = fminf(fmaxf(c, -15.0f), 15.0f);
            float eo = __builtin_amdgcn_exp2f(ao);   // e^{-o}
            float ec = __builtin_amdgcn_exp2f(cc * (2.0f * L2E));
            float rh = __builtin_amdgcn_rcpf((1.0f + eo) * (1.0f + ec));
            float hv = (ec - 1.0f) * rh;             // sig(o)*tanh(c)
            hsh[wid][lane] = (_Float16)hv;
            asm volatile("" ::: "memory");           // keep write->read order
        }
    }

    // ---- head: 2 batches/wave; lane j=lane&31 (unit), g0=lane>>5 (batch)
    const int j  = lane & 31;
    const int g0 = lane >> 5;
    float a = b3[j];
    #pragma unroll
    for (int k = 0; k < 32; ++k)
        a = fmaf((float)hsh[wid][g0 * 32 + k], W3[j * 32 + k], a);
    a = fmaxf(a, 0.0f);
    float v = a * W4[j];
    #pragma unroll
    for (int off = 16; off >= 1; off >>= 1)   // stays within 32-lane halves
        v += __shfl_xor(v, off);
    if ((lane & 31) == 0) {
        float e = __builtin_amdgcn_exp2f(-(v + b4[0]) * L2E);
        out[wb + g0] = __builtin_amdgcn_rcpf(1.0f + e);
    }
}

extern "C" void kernel_launch(void* const* d_in, const int* in_sizes, int n_in,
                              void* d_out, int out_size, void* d_ws, size_t ws_size,
                              hipStream_t stream) {
    const float* x    = (const float*)d_in[0];
    const float* W_ih = (const float*)d_in[1];
    const float* W_hh = (const float*)d_in[2];
    const float* b_ih = (const float*)d_in[3];
    const float* b_hh = (const float*)d_in[4];
    const float* W3   = (const float*)d_in[5];
    const float* b3   = (const float*)d_in[6];
    const float* W4   = (const float*)d_in[7];
    const float* b4   = (const float*)d_in[8];
    float* out = (float*)d_out;

    const int batches = out_size;          // 8192
    const int blocks  = batches / 8;       // 1024 WGs x 4 waves x 2 batches
    lstm_v8<<<blocks, 256, 0, stream>>>(x, W_ih, W_hh, b_ih, b_hh,
                                        W3, b3, W4, b4, out);
}